// Round 2
// baseline (780.914 us; speedup 1.0000x reference)
//
#include <hip/hip_runtime.h>
#include <hip/hip_bf16.h>

#define BN 8
#define SS 1024
#define CC 512
#define HH 8
#define DD 64
#define PP 16
#define KT 1040

typedef __hip_bfloat16 bf16;
typedef unsigned char uchar;
typedef unsigned short ushort;
typedef unsigned int uint;
typedef __attribute__((ext_vector_type(8))) short short8;
typedef __attribute__((ext_vector_type(4))) float f32x4;
typedef __attribute__((ext_vector_type(2))) float f32x2;

__device__ __forceinline__ short f2s(float v){ bf16 b = __float2bfloat16(v); return *(short*)&b; }
__device__ __forceinline__ float s2f(short s){ bf16 b; *(short*)&b = s; return __bfloat162float(b); }
__device__ __forceinline__ uchar f2q(float v){          // f32 -> fp8 e4m3 byte
    return (uchar)__builtin_amdgcn_cvt_pk_fp8_f32(v, v, 0, false);
}
__device__ __forceinline__ float rfl(float x){          // force to SGPR
    return __int_as_float(__builtin_amdgcn_readfirstlane(__float_as_int(x)));
}

#define MFMA16(a,b,c)  __builtin_amdgcn_mfma_f32_16x16x32_bf16(a,b,c,0,0,0)
#define MFMAF8(a,b,c)  __builtin_amdgcn_mfma_f32_16x16x32_fp8_fp8(a,b,c,0,0,0)

// ---------------------------------------------------------------------------
// P0: weight pre-conversion + persistent-token tails.
// ---------------------------------------------------------------------------
__global__ __launch_bounds__(256) void prep_kernel(
    const float* __restrict__ fc_w, const float* __restrict__ c1w,
    const float* __restrict__ c2w, const float* __restrict__ Wq,
    const float* __restrict__ Wk, const float* __restrict__ Wv,
    const float* __restrict__ th_post,
    const float* __restrict__ pk, const float* __restrict__ pv,
    short* __restrict__ Bfc, uchar* __restrict__ Bc1,
    uchar* __restrict__ Bc2, short* __restrict__ Bqkv,
    uchar* __restrict__ kf, uchar* __restrict__ vt)
{
    int i = blockIdx.x*256 + threadIdx.x;
    const int NFC = 512*512, NCV = 512*1536, NQ = 3*64*64, NP = BN*HH*PP*DD;
    if (i < NFC) {
        int c = i >> 9, r = i & 511;
        int g = r >> 6, d = r & 63;
        float s = 0.f;
        #pragma unroll
        for (int h = 0; h < 8; ++h)
            s += fc_w[(size_t)c*512 + h*64 + d] * th_post[h*8 + g];
        Bfc[i] = f2s(s);
        return;
    }
    i -= NFC;
    if (i < NCV) {
        int o = i/1536, r = i%1536, dk = r>>9, ci = r&511;
        Bc1[i] = f2q(c1w[(o*512+ci)*3+dk] * 16.f); return;
    }
    i -= NCV;
    if (i < NCV) {
        int o = i/1536, r = i%1536, dk = r>>9, ci = r&511;
        Bc2[i] = f2q(c2w[(o*512+ci)*3+dk] * 16.f); return;
    }
    i -= NCV;
    if (i < NQ) {
        int w = i >> 12, rest = i & 4095;
        const float* W = (w==0)?Wq:(w==1)?Wk:Wv;
        Bqkv[i] = f2s(W[((rest>>6)&63)*64 + (rest&63)]);
        return;
    }
    i -= NQ;
    if (i < NP) {
        int d = i & 63, p = (i >> 6) & 15, h = (i >> 10) & 7, n = i >> 13;
        size_t src = ((size_t)p*HH + h)*DD + d;
        kf[(((size_t)(n*HH+h))*KT + SS + p)*DD + d] = f2q(pk[src]);
        vt[(((size_t)(n*HH+h))*DD + d)*KT + SS + p] = f2q(pv[src]);
    }
}

// ---------------------------------------------------------------------------
// K1 v2: QKV projection, bf16 MFMA, XCD-swizzled.
// q/k out fp8 [s][d]; V -> transposed fp8 vt[nh][d][k=s].
// ---------------------------------------------------------------------------
__global__ __launch_bounds__(256) void qkv_mfma(
    const float* __restrict__ x, const short* __restrict__ Bqkv,
    uchar* __restrict__ qf, uchar* __restrict__ kf, uchar* __restrict__ vt)
{
    __shared__ short Xs[64*72];
    __shared__ short Ws[192*72];
    const int tid = threadIdx.x;
    const int lin = blockIdx.x;                     // grid 1024 linear
    const int xcd = lin & 7, slot = lin >> 3;       // slot in [0,128)
    const int m0 = (xcd*16 + (slot & 15))*64;
    const int h = slot >> 4;
    const int wave = tid >> 6, lane = tid & 63;
    const int lr = lane & 15, lq = lane >> 4;

    for (int i = tid; i < 1024; i += 256) {
        int r = i >> 4, cg = (i & 15)*4;
        float4 v = *(const float4*)(x + (size_t)(m0+r)*CC + h*64 + cg);
        Xs[r*72+cg+0] = f2s(v.x); Xs[r*72+cg+1] = f2s(v.y);
        Xs[r*72+cg+2] = f2s(v.z); Xs[r*72+cg+3] = f2s(v.w);
    }
    for (int i = tid; i < 3072; i += 256) {
        int r = i >> 4, cg = (i & 15)*4;
        *(short4*)(Ws + r*72 + cg) = *(const short4*)(Bqkv + (size_t)r*64 + cg);
    }
    __syncthreads();

    f32x4 acc[12];
    #pragma unroll
    for (int nt = 0; nt < 12; ++nt) acc[nt] = {0.f,0.f,0.f,0.f};
    #pragma unroll
    for (int ks = 0; ks < 2; ++ks) {
        int ko = ks*32 + lq*8;
        short8 a = *(const short8*)(Xs + (wave*16 + lr)*72 + ko);
        #pragma unroll
        for (int nt = 0; nt < 12; ++nt) {
            short8 b = *(const short8*)(Ws + (nt*16 + lr)*72 + ko);
            acc[nt] = MFMA16(a, b, acc[nt]);
        }
    }
    #pragma unroll
    for (int nt = 0; nt < 12; ++nt) {
        int ep = nt*16 + lr;
        int w = ep >> 6, e = ep & 63;
        #pragma unroll
        for (int reg = 0; reg < 4; ++reg) {
            int m = m0 + wave*16 + lq*4 + reg;
            int n = m >> 10, s = m & 1023;
            float v = acc[nt][reg];
            if (w == 0)      qf[((size_t)(n*HH+h)*SS + s)*DD + e] = f2q(v);
            else if (w == 1) kf[((size_t)(n*HH+h)*KT + s)*DD + e] = f2q(v);
            else             vt[(((size_t)(n*HH+h))*DD + e)*KT + s] = f2q(v);
        }
    }
}

// ---------------------------------------------------------------------------
// K2 v3: energy (RAW, pre-mix), fp8 MFMA NT, XCD-swizzled.
// ---------------------------------------------------------------------------
__device__ __forceinline__ void en_loadK(const uchar* __restrict__ kf,
    int nh, int kt, int tid, uint2* rk)
{
    #pragma unroll
    for (int j = 0; j < 2; ++j) {
        int i = tid + j*256;
        int r = i >> 3, c8 = (i & 7)*8;
        int kcol = kt*64 + r;
        uint2 v = {0u, 0u};
        if (kcol < KT)
            v = *(const uint2*)(kf + ((size_t)nh*KT + kcol)*DD + c8);
        rk[j] = v;
    }
}

__global__ __launch_bounds__(256) void energy_mfma8(
    const uchar* __restrict__ qf, const uchar* __restrict__ kf,
    uchar* __restrict__ E)
{
    __shared__ uchar Qs[64*72];
    __shared__ uchar Ks[64*72];
    const int tid = threadIdx.x;
    const int lin = blockIdx.x + 16*blockIdx.y;     // grid (16, 64)
    const int xcd = lin & 7, slot = lin >> 3;       // slot in [0,128)
    const int nh = xcd*8 + (slot & 7);
    const int mt = slot >> 3;
    const int wave = tid >> 6, lane = tid & 63;
    const int lr = lane & 15, lq = lane >> 4;
    const int n = nh >> 3, h = nh & 7;

    #pragma unroll
    for (int j = 0; j < 2; ++j) {
        int i = tid + j*256;
        int r = i >> 3, c8 = (i & 7)*8;
        *(uint2*)(Qs + r*72 + c8) =
            *(const uint2*)(qf + ((size_t)nh*SS + mt*64 + r)*DD + c8);
    }

    uint2 rk[2];
    en_loadK(kf, nh, 0, tid, rk);

    for (int kt = 0; kt < 17; ++kt) {
        if (kt) __syncthreads();
        #pragma unroll
        for (int j = 0; j < 2; ++j) {
            int i = tid + j*256;
            *(uint2*)(Ks + (i >> 3)*72 + (i & 7)*8) = rk[j];
        }
        __syncthreads();
        if (kt + 1 < 17) en_loadK(kf, nh, kt+1, tid, rk);

        f32x4 acc[4];
        #pragma unroll
        for (int nt = 0; nt < 4; ++nt) acc[nt] = {0.f,0.f,0.f,0.f};
        #pragma unroll
        for (int ks = 0; ks < 2; ++ks) {
            int ko = ks*32 + lq*8;
            long a = *(const long*)(Qs + (wave*16 + lr)*72 + ko);
            #pragma unroll
            for (int nt = 0; nt < 4; ++nt) {
                long b = *(const long*)(Ks + (nt*16 + lr)*72 + ko);
                acc[nt] = MFMAF8(a, b, acc[nt]);
            }
        }
        #pragma unroll
        for (int nt = 0; nt < 4; ++nt) {
            int kcol = kt*64 + nt*16 + lr;
            if (kcol >= KT) continue;
            #pragma unroll
            for (int reg = 0; reg < 4; ++reg) {
                int q = mt*64 + wave*16 + lq*4 + reg;
                E[(((size_t)(n*SS + q))*HH + h)*KT + kcol] = f2q(acc[nt][reg]);
            }
        }
    }
}

// ---------------------------------------------------------------------------
// K3+K4 fused: pv_fused — per block: (n, 16 q-rows) x all 8 heads.
// Reads RAW E fp8, premix (8x8 talking heads, SGPR weights) + ALiBi + mask +
// exp in registers, writes SHIFTED-unnormalized p fp8 to LDS in MFMA A-frag
// layout, PV via fp8 MFMA, divides by the running row-sum in the epilogue.
//
// Range control: slmix[h] (talking-heads-mixed ALiBi slope) can be NEGATIVE,
// so exp2 can reach 2^+13 at far distance -> fp8 saturation. Fix: subtract
// the ANALYTIC per-(h,q) bound shift = max(0, -slmix[h]*maxdist(q)) inside
// the exp; it cancels exactly in the normalization. e' <= ~1.2 -> fp8-safe.
// Grid dim3(8,64): blockIdx.x = n (1 n per XCD -> V tile L2-resident).
// ---------------------------------------------------------------------------
__device__ __forceinline__ void pvf_loadE(const uchar* __restrict__ Eb,
    int kt, int k4, uint* rE)
{
    int kb = kt*64 + k4;
    if (kb < KT) {
        #pragma unroll
        for (int g = 0; g < 8; ++g)
            rE[g] = *(const uint*)(Eb + (size_t)g*KT + kb);
    } else {
        #pragma unroll
        for (int g = 0; g < 8; ++g) rE[g] = 0u;
    }
}
__device__ __forceinline__ void pvf_loadV(const uchar* __restrict__ vtb,
    int kt, int tid, uint4* rv)
{
    #pragma unroll
    for (int j = 0; j < 8; ++j) {
        int i = tid + j*256;
        rv[j] = *(const uint4*)(vtb + (size_t)(i >> 2)*KT + kt*64 + (i & 3)*16);
    }
}

__global__ __launch_bounds__(256, 2) void pv_fused(
    const uchar* __restrict__ E, const uchar* __restrict__ vt,
    const int* __restrict__ mask, const float* __restrict__ th_pre,
    short* __restrict__ AO)
{
    __shared__ uchar Ps[8*16*72];        //  9 KB: p fp8, [h][q16][72]
    __shared__ uchar Vs[8*64*72];        // 36 KB: v fp8, [h*64+d][72]
    __shared__ float Sred[16][8];        // 1/rowsum per (q,h)
    const int tid  = threadIdx.x;
    const int n    = blockIdx.x;         // 8  (== XCD)
    const int ql0  = blockIdx.y * 16;    // 64 q-tiles
    const int wave = tid >> 6, lane = tid & 63;
    const int lr = lane & 15, lq = lane >> 4;
    const int q_l = tid >> 4, kq = tid & 15, k4 = kq*4;
    const int q = ql0 + q_l;

    // scaled talking-heads weights + mixed ALiBi slopes -> SGPRs
    const float sc = 0.044194173824159216f * 1.4426950408889634f; // 1/sqrt(C)*log2e
    float thp_s[64], slmix_s[8], shift_s[8];
    {
        const float slv[8] = {0.5f,0.25f,0.125f,0.0625f,
                              0.03125f,0.015625f,0.0078125f,0.00390625f};
        const float maxd = (float)((q > SS-1-q) ? q : (SS-1-q));
        #pragma unroll
        for (int h = 0; h < 8; ++h) {
            float sm = 0.f;
            #pragma unroll
            for (int g = 0; g < 8; ++g) {
                float v = rfl(th_pre[h*8+g] * sc);
                thp_s[h*8+g] = v;
                sm += v * slv[g];
            }
            slmix_s[h] = rfl(sm);
            shift_s[h] = fmaxf(0.f, -slmix_s[h] * maxd);   // per-thread (q)
        }
    }

    const uchar* Eb  = E  + ((size_t)(n*SS + q))*HH*KT;   // head-0 row, this q
    const uchar* vtb = vt + (size_t)n*HH*DD*KT;
    const int*  mrow = mask + (size_t)n*SS*SS + (size_t)q*SS;

    uint  rE[8]; uint4 rv[8]; int4 rm;
    pvf_loadE(Eb, 0, k4, rE);
    pvf_loadV(vtb, 0, tid, rv);
    rm = *(const int4*)(mrow + k4);

    f32x4 sums4[8];
    #pragma unroll
    for (int h = 0; h < 8; ++h) sums4[h] = {0.f,0.f,0.f,0.f};
    f32x4 acc[2][4];
    #pragma unroll
    for (int i = 0; i < 2; ++i)
        #pragma unroll
        for (int j = 0; j < 4; ++j) acc[i][j] = {0.f,0.f,0.f,0.f};

    for (int kt = 0; kt < 17; ++kt) {
        // ---- premix + shifted softmax numerator (registers only)
        uint pb[8];
        {
            f32x4 a[8];
            #pragma unroll
            for (int g = 0; g < 8; ++g) {
                f32x2 lo = __builtin_amdgcn_cvt_pk_f32_fp8((int)rE[g], false);
                f32x2 hi = __builtin_amdgcn_cvt_pk_f32_fp8((int)rE[g], true);
                f32x4 r; r.x = lo.x; r.y = lo.y; r.z = hi.x; r.w = hi.y;
                a[g] = r;
            }
            const bool body = (kt < 16);
            const bool pvalid = (kt*64 + k4) < KT;   // tail tile: 16 valid cols
            float kb = (float)(kt*64 + k4), qv = (float)q;
            f32x4 dist;
            dist.x = fabsf(qv - kb);       dist.y = fabsf(qv - kb - 1.f);
            dist.z = fabsf(qv - kb - 2.f); dist.w = fabsf(qv - kb - 3.f);
            #pragma unroll
            for (int h = 0; h < 8; ++h) {
                f32x4 t = {0.f,0.f,0.f,0.f};
                #pragma unroll
                for (int g = 0; g < 8; ++g) t += a[g] * thp_s[h*8+g];
                const float shf = shift_s[h];
                f32x4 e;
                if (body) {
                    t -= dist * slmix_s[h];
                    e.x = (rm.x == 0) ? 0.f : exp2f(t.x - shf);
                    e.y = (rm.y == 0) ? 0.f : exp2f(t.y - shf);
                    e.z = (rm.z == 0) ? 0.f : exp2f(t.z - shf);
                    e.w = (rm.w == 0) ? 0.f : exp2f(t.w - shf);
                } else if (pvalid) {       // persistent keys: no bias, no mask
                    e.x = exp2f(t.x - shf); e.y = exp2f(t.y - shf);
                    e.z = exp2f(t.z - shf); e.w = exp2f(t.w - shf);
                } else {
                    e = {0.f,0.f,0.f,0.f};
                }
                sums4[h] += e;
                int p0 = __builtin_amdgcn_cvt_pk_fp8_f32(e.x, e.y, 0, false);
                p0 = __builtin_amdgcn_cvt_pk_fp8_f32(e.z, e.w, p0, true);
                pb[h] = (uint)p0;
            }
        }
        __syncthreads();                   // prev MFMA done reading LDS
        #pragma unroll
        for (int h = 0; h < 8; ++h)
            *(uint*)(Ps + h*1152 + q_l*72 + k4) = pb[h];
        #pragma unroll
        for (int j = 0; j < 8; ++j) {
            int i = tid + j*256;
            uchar* d = Vs + (i >> 2)*72 + (i & 3)*16;
            uint2 lo; lo.x = rv[j].x; lo.y = rv[j].y;
            uint2 hi; hi.x = rv[j].z; hi.y = rv[j].w;
            *(uint2*)(d) = lo; *(uint2*)(d + 8) = hi;
        }
        __syncthreads();
        if (kt + 1 < 17) {                 // prefetch next tile (covers MFMA)
            pvf_loadE(Eb, kt+1, k4, rE);
            pvf_loadV(vtb, kt+1, tid, rv);
            if (kt + 1 < 16) rm = *(const int4*)(mrow + (kt+1)*64 + k4);
        }
        #pragma unroll
        for (int h2 = 0; h2 < 2; ++h2) {   // wave owns heads wave*2, wave*2+1
            const uchar* Ph = Ps + (wave*2 + h2)*1152;
            const uchar* Vh = Vs + (wave*2 + h2)*4608;
            #pragma unroll
            for (int ks = 0; ks < 2; ++ks) {
                int ko = ks*32 + lq*8;
                long av = *(const long*)(Ph + lr*72 + ko);
                #pragma unroll
                for (int nt = 0; nt < 4; ++nt) {
                    long bv = *(const long*)(Vh + (nt*16 + lr)*72 + ko);
                    acc[h2][nt] = MFMAF8(av, bv, acc[h2][nt]);
                }
            }
        }
    }

    // ---- row sums: horizontal + 16-lane shuffle reduce -> 1/sum in LDS
    #pragma unroll
    for (int h = 0; h < 8; ++h) {
        float s = sums4[h].x + sums4[h].y + sums4[h].z + sums4[h].w;
        s += __shfl_xor(s, 1); s += __shfl_xor(s, 2);
        s += __shfl_xor(s, 4); s += __shfl_xor(s, 8);
        if (kq == 0) Sred[q_l][h] = 1.0f / s;
    }
    __syncthreads();

    // ---- normalize + store AO (bf16)
    #pragma unroll
    for (int h2 = 0; h2 < 2; ++h2) {
        int h = wave*2 + h2;
        #pragma unroll
        for (int reg = 0; reg < 4; ++reg) {
            float inv = Sred[lq*4 + reg][h];
            int qg = ql0 + lq*4 + reg;
            #pragma unroll
            for (int nt = 0; nt < 4; ++nt) {
                int d = nt*16 + lr;
                AO[((size_t)(n*SS) + qg)*CC + h*64 + d] =
                    f2s(acc[h2][nt][reg] * inv);
            }
        }
    }
}

// ---------------------------------------------------------------------------
// K5: fc (th_post folded into weights), bf16 MFMA, 64x64, XCD-swizzled.
// ---------------------------------------------------------------------------
__device__ __forceinline__ void g_load4(const short* __restrict__ src,
    size_t rowstride, int row0, int col0, int tid, short4* r)
{
    #pragma unroll
    for (int j = 0; j < 4; ++j) {
        int i = tid + j*256;
        int rr = i >> 4, cg = (i & 15)*4;
        r[j] = *(const short4*)(src + (size_t)(row0 + rr)*rowstride + col0 + cg);
    }
}
__device__ __forceinline__ void lds_store4(short* __restrict__ dst,
    int tid, const short4* r)
{
    #pragma unroll
    for (int j = 0; j < 4; ++j) {
        int i = tid + j*256;
        *(short4*)(dst + (i >> 4)*72 + (i & 15)*4) = r[j];
    }
}

__global__ __launch_bounds__(256) void fc_mfma(
    const short* __restrict__ A, const short* __restrict__ Bt,
    const float* __restrict__ bias, const float* __restrict__ x,
    short* __restrict__ out, uchar* __restrict__ out8)
{
    __shared__ short As[64*72];
    __shared__ short Bs[64*72];
    const int tid = threadIdx.x;
    const int lin = blockIdx.x + 8*blockIdx.y;      // grid (8,128)
    const int xcd = lin & 7, slot = lin >> 3;
    const int m0 = (xcd*16 + (slot & 15))*64;
    const int n0 = (slot >> 4)*64;
    const int wave = tid >> 6, lane = tid & 63;
    const int lr = lane & 15, lq = lane >> 4;

    short4 ra[4], rb[4];
    g_load4(A, CC, m0, 0, tid, ra);
    g_load4(Bt, CC, n0, 0, tid, rb);

    f32x4 acc[4];
    #pragma unroll
    for (int nt = 0; nt < 4; ++nt) acc[nt] = {0.f,0.f,0.f,0.f};

    for (int kt = 0; kt < CC; kt += 64) {
        if (kt) __syncthreads();
        lds_store4(As, tid, ra);
        lds_store4(Bs, tid, rb);
        __syncthreads();
        if (kt + 64 < CC) {
            g_load4(A, CC, m0, kt+64, tid, ra);
            g_load4(Bt, CC, n0, kt+64, tid, rb);
        }
        #pragma unroll
        for (int ks = 0; ks < 2; ++ks) {
            int ko = ks*32 + lq*8;
            short8 a = *(const short8*)(As + (wave*16 + lr)*72 + ko);
            #pragma unroll
            for (int nt = 0; nt < 4; ++nt) {
                short8 b = *(const short8*)(Bs + (nt*16 + lr)*72 + ko);
                acc[nt] = MFMA16(a, b, acc[nt]);
            }
        }
    }
    #pragma unroll
    for (int nt = 0; nt < 4; ++nt) {
        int nn = n0 + nt*16 + lr;
        #pragma unroll
        for (int reg = 0; reg < 4; ++reg) {
            int m = m0 + wave*16 + lq*4 + reg;
            float v = acc[nt][reg] + bias[nn] + x[(size_t)m*CC + nn];
            out[(size_t)m*CC + nn]  = f2s(v);
            out8[(size_t)m*CC + nn] = f2q(v);
        }
    }
}

// ---------------------------------------------------------------------------
// K6 v2: causal conv fp8 NT GEMM, BK=128 (12 K-iters), XCD-swizzled.
// ---------------------------------------------------------------------------
__device__ __forceinline__ void conv_loadA8w(const uchar* __restrict__ A,
    int m0, int kt, int tid, uint2* ra)
{
    const int shift = (kt >> 9) - 2;
    const int ci0 = kt & 511;
    #pragma unroll
    for (int j = 0; j < 4; ++j) {
        int i = tid + j*256;
        int rr = i >> 4, c8 = (i & 15)*8;
        int m = m0 + rr;
        int s = m & (SS-1);
        uint2 v = {0u, 0u};
        if (s + shift >= 0)
            v = *(const uint2*)(A + (size_t)(m + shift)*CC + ci0 + c8);
        ra[j] = v;
    }
}
__device__ __forceinline__ void g_load8w(const uchar* __restrict__ src,
    size_t rowstride, int row0, int col0, int tid, uint2* r)
{
    #pragma unroll
    for (int j = 0; j < 4; ++j) {
        int i = tid + j*256;
        int rr = i >> 4, c8 = (i & 15)*8;
        r[j] = *(const uint2*)(src + (size_t)(row0 + rr)*rowstride + col0 + c8);
    }
}
__device__ __forceinline__ void lds_store8w(uchar* __restrict__ dst,
    int tid, const uint2* r)
{
    #pragma unroll
    for (int j = 0; j < 4; ++j) {
        int i = tid + j*256;
        *(uint2*)(dst + (i >> 4)*136 + (i & 15)*8) = r[j];
    }
}

__global__ __launch_bounds__(256) void conv_mfma8(
    const uchar* __restrict__ A, const uchar* __restrict__ Bt,
    const float* __restrict__ bias, uchar* __restrict__ out8,
    short* __restrict__ out16, int f8out)
{
    __shared__ uchar As[64*136];
    __shared__ uchar Bs[64*136];
    const int tid = threadIdx.x;
    const int lin = blockIdx.x + 8*blockIdx.y;      // grid (8,128)
    const int xcd = lin & 7, slot = lin >> 3;
    const int m0 = (xcd*16 + (slot & 15))*64;
    const int n0 = (slot >> 4)*64;
    const int wave = tid >> 6, lane = tid & 63;
    const int lr = lane & 15, lq = lane >> 4;

    uint2 ra[4], rb[4];
    conv_loadA8w(A, m0, 0, tid, ra);
    g_load8w(Bt, 1536, n0, 0, tid, rb);

    f32x4 acc[4];
    #pragma unroll
    for (int nt = 0; nt < 4; ++nt) acc[nt] = {0.f,0.f,0.f,0.f};

    for (int kt = 0; kt < 1536; kt += 128) {
        if (kt) __syncthreads();
        lds_store8w(As, tid, ra);
        lds_store8w(Bs, tid, rb);
        __syncthreads();
        if (kt + 128 < 1536) {
            conv_loadA8w(A, m0, kt+128, tid, ra);
            g_load8w(Bt, 1536, n0, kt+128, tid, rb);
        }
        #pragma unroll
        for (int ks = 0; ks < 4; ++ks) {
            int ko = ks*32 + lq*8;
            long a = *(const long*)(As + (wave*16 + lr)*136 + ko);
            #pragma unroll
            for (int nt = 0; nt < 4; ++nt) {
                long b = *(const long*)(Bs + (nt*16 + lr)*136 + ko);
                acc[nt] = MFMAF8(a, b, acc[nt]);
            }
        }
    }
    #pragma unroll
    for (int nt = 0; nt < 4; ++nt) {
        int nn = n0 + nt*16 + lr;
        #pragma unroll
        for (int reg = 0; reg < 4; ++reg) {
            int m = m0 + wave*16 + lq*4 + reg;
            float v = fmaxf(acc[nt][reg]*0.0625f + bias[nn], 0.f);
            if (f8out) out8[(size_t)m*CC + nn]  = f2q(v);
            else       out16[(size_t)m*CC + nn] = f2s(v);
        }
    }
}

// ---------------------------------------------------------------------------
// K7: out = LN(relu(c2 + xres) masked) * g + b.  4 rows per block.
// ---------------------------------------------------------------------------
__global__ __launch_bounds__(256) void final_kernel(
    const short* __restrict__ c2, const short* __restrict__ xres,
    const int* __restrict__ mask, const float* __restrict__ g,
    const float* __restrict__ b, float* __restrict__ out)
{
    __shared__ float red[256];
    const int tid = threadIdx.x;
    const int m0 = blockIdx.x * 4;
    const int c0 = tid*2;
    const float2 gg = *(const float2*)(g + c0);
    const float2 bb = *(const float2*)(b + c0);

    for (int rr = 0; rr < 4; ++rr) {
        const int m = m0 + rr;
        const int n = m >> 10, s = m & 1023;
        const int mk = mask[(size_t)n*SS*SS + (size_t)s*SS];

        short2 ca = *(const short2*)(c2 + (size_t)m*CC + c0);
        short2 xa = *(const short2*)(xres + (size_t)m*CC + c0);
        float v0 = fmaxf(s2f(ca.x) + s2f(xa.x), 0.f);
        float v1 = fmaxf(s2f(ca.y) + s2f(xa.y), 0.f);
        if (mk == 0) { v0 = 0.f; v1 = 0.f; }

        red[tid] = v0 + v1;
        __syncthreads();
        for (int off = 128; off > 0; off >>= 1) {
            if (tid < off) red[tid] += red[tid + off];
            __syncthreads();
        }
        float mu = red[0] * (1.0f/512.0f);
        __syncthreads();
        float d0 = v0 - mu, d1 = v1 - mu;
        red[tid] = d0*d0 + d1*d1;
        __syncthreads();
        for (int off = 128; off > 0; off >>= 1) {
            if (tid < off) red[tid] += red[tid + off];
            __syncthreads();
        }
        float rstd = rsqrtf(red[0] * (1.0f/512.0f) + 1e-5f);
        float2 o;
        o.x = d0*rstd*gg.x + bb.x;
        o.y = d1*rstd*gg.y + bb.y;
        *(float2*)(out + (size_t)m*CC + c0) = o;
        __syncthreads();                     // red reuse next row
    }
}

// ---------------------------------------------------------------------------
extern "C" void kernel_launch(void* const* d_in, const int* in_sizes, int n_in,
                              void* d_out, int out_size, void* d_ws, size_t ws_size,
                              hipStream_t stream)
{
    const float* x      = (const float*)d_in[0];
    const int*   mask   = (const int*)  d_in[1];
    const float* Wq     = (const float*)d_in[2];
    const float* Wk     = (const float*)d_in[3];
    const float* Wv     = (const float*)d_in[4];
    const float* pk     = (const float*)d_in[5];
    const float* pv     = (const float*)d_in[6];
    const float* th_pre = (const float*)d_in[7];
    const float* th_post= (const float*)d_in[8];
    const float* fc_w   = (const float*)d_in[9];
    const float* fc_b   = (const float*)d_in[10];
    const float* c1w    = (const float*)d_in[11];
    const float* c1b    = (const float*)d_in[12];
    const float* c2w    = (const float*)d_in[13];
    const float* c2b    = (const float*)d_in[14];
    const float* lng    = (const float*)d_in[15];
    const float* lnb    = (const float*)d_in[16];
    float* out = (float*)d_out;
    (void)in_sizes; (void)n_in; (void)out_size; (void)ws_size;

    char* ws = (char*)d_ws;
    const size_t SZ_Q  = (size_t)BN*HH*SS*DD;      //  4.19 MB (fp8)
    const size_t SZ_K  = (size_t)BN*HH*KT*DD;      //  4.26 MB (fp8)
    const size_t SZ_VT = (size_t)BN*HH*DD*KT;      //  4.26 MB (fp8)
    const size_t SZ_E  = (size_t)BN*SS*HH*KT;      // 68.2 MB (fp8, raw energy)
    const size_t SZ_A  = (size_t)BN*SS*CC*2;       //  8.39 MB (bf16)
    const size_t SZ_A8 = (size_t)BN*SS*CC;         //  4.19 MB (fp8)

    uchar* qf  = (uchar*)(ws);
    uchar* kf  = (uchar*)(ws + SZ_Q);
    uchar* vt  = (uchar*)(ws + SZ_Q + SZ_K);
    uchar* E   = (uchar*)(ws + SZ_Q + SZ_K + SZ_VT);
    short* AO  = (short*)(ws + SZ_Q + SZ_K + SZ_VT + SZ_E);
    char*  wend = ws + SZ_Q + SZ_K + SZ_VT + SZ_E + SZ_A;
    short* Bfc = (short*)(wend);
    uchar* Bc1 = (uchar*)(wend + 512*512*2);
    uchar* Bc2 = (uchar*)(wend + 512*512*2 + 512*1536);
    short* Bqkv= (short*)(wend + 512*512*2 + 2*512*1536);
    uchar* xres8 = (uchar*)(wend + 512*512*2 + 2*512*1536 + 3*64*64*2);
    short* c2buf = (short*)(wend + 512*512*2 + 2*512*1536 + 3*64*64*2 + SZ_A8);
    // Aliases (dead regions): xres(bf16) over qf+kf (dead after energy);
    // h1(fp8) over E (dead after pv_fused).
    short* xres = (short*)(ws);
    uchar* h18  = (uchar*)E;
    // total ws ~= 103 MB (ws_size >= 256 MiB)

    {
        int total = 512*512 + 2*512*1536 + 3*64*64 + BN*HH*PP*DD;
        prep_kernel<<<(total + 255)/256, 256, 0, stream>>>(
            fc_w, c1w, c2w, Wq, Wk, Wv, th_post, pk, pv,
            Bfc, Bc1, Bc2, Bqkv, kf, vt);
    }
    qkv_mfma<<<BN*SS/64*HH, 256, 0, stream>>>(x, Bqkv, qf, kf, vt);

    energy_mfma8<<<dim3(16, 64), 256, 0, stream>>>(qf, kf, E);
    pv_fused<<<dim3(8, 64), 256, 0, stream>>>(E, vt, mask, th_pre, AO);

    fc_mfma<<<dim3(8, 128), 256, 0, stream>>>(AO, Bfc, fc_b, x, xres, xres8);
    conv_mfma8<<<dim3(8, 128), 256, 0, stream>>>(xres8, Bc1, c1b, h18, (short*)nullptr, 1);
    conv_mfma8<<<dim3(8, 128), 256, 0, stream>>>(h18, Bc2, c2b, (uchar*)nullptr, c2buf, 0);
    final_kernel<<<BN*SS/4, 256, 0, stream>>>(c2buf, xres, mask, lng, lnb, out);
}

// Round 3
// 583.228 us; speedup vs baseline: 1.3390x; 1.3390x over previous
//
#include <hip/hip_runtime.h>
#include <hip/hip_bf16.h>

#define BN 8
#define SS 1024
#define CC 512
#define HH 8
#define DD 64
#define PP 16
#define KT 1040
#define KTE 1088   // E head-row stride, padded to 64B multiple

typedef __hip_bfloat16 bf16;
typedef unsigned char uchar;
typedef unsigned short ushort;
typedef unsigned int uint;
typedef __attribute__((ext_vector_type(8))) short short8;
typedef __attribute__((ext_vector_type(4))) float f32x4;
typedef __attribute__((ext_vector_type(2))) float f32x2;

__device__ __forceinline__ short f2s(float v){ bf16 b = __float2bfloat16(v); return *(short*)&b; }
__device__ __forceinline__ float s2f(short s){ bf16 b; *(short*)&b = s; return __bfloat162float(b); }
__device__ __forceinline__ uchar f2q(float v){          // f32 -> fp8 e4m3 byte
    return (uchar)__builtin_amdgcn_cvt_pk_fp8_f32(v, v, 0, false);
}
__device__ __forceinline__ float rfl(float x){          // force to SGPR
    return __int_as_float(__builtin_amdgcn_readfirstlane(__float_as_int(x)));
}

#define MFMA16(a,b,c)  __builtin_amdgcn_mfma_f32_16x16x32_bf16(a,b,c,0,0,0)
#define MFMAF8(a,b,c)  __builtin_amdgcn_mfma_f32_16x16x32_fp8_fp8(a,b,c,0,0,0)

// ---------------------------------------------------------------------------
// P0: weight pre-conversion + persistent-token tails.
// ---------------------------------------------------------------------------
__global__ __launch_bounds__(256) void prep_kernel(
    const float* __restrict__ fc_w, const float* __restrict__ c1w,
    const float* __restrict__ c2w, const float* __restrict__ Wq,
    const float* __restrict__ Wk, const float* __restrict__ Wv,
    const float* __restrict__ th_post,
    const float* __restrict__ pk, const float* __restrict__ pv,
    short* __restrict__ Bfc, uchar* __restrict__ Bc1,
    uchar* __restrict__ Bc2, short* __restrict__ Bqkv,
    uchar* __restrict__ kf, uchar* __restrict__ vt)
{
    int i = blockIdx.x*256 + threadIdx.x;
    const int NFC = 512*512, NCV = 512*1536, NQ = 3*64*64, NP = BN*HH*PP*DD;
    if (i < NFC) {
        int c = i >> 9, r = i & 511;
        int g = r >> 6, d = r & 63;
        float s = 0.f;
        #pragma unroll
        for (int h = 0; h < 8; ++h)
            s += fc_w[(size_t)c*512 + h*64 + d] * th_post[h*8 + g];
        Bfc[i] = f2s(s);
        return;
    }
    i -= NFC;
    if (i < NCV) {
        int o = i/1536, r = i%1536, dk = r>>9, ci = r&511;
        Bc1[i] = f2q(c1w[(o*512+ci)*3+dk] * 16.f); return;
    }
    i -= NCV;
    if (i < NCV) {
        int o = i/1536, r = i%1536, dk = r>>9, ci = r&511;
        Bc2[i] = f2q(c2w[(o*512+ci)*3+dk] * 16.f); return;
    }
    i -= NCV;
    if (i < NQ) {
        int w = i >> 12, rest = i & 4095;
        const float* W = (w==0)?Wq:(w==1)?Wk:Wv;
        Bqkv[i] = f2s(W[((rest>>6)&63)*64 + (rest&63)]);
        return;
    }
    i -= NQ;
    if (i < NP) {
        int d = i & 63, p = (i >> 6) & 15, h = (i >> 10) & 7, n = i >> 13;
        size_t src = ((size_t)p*HH + h)*DD + d;
        kf[(((size_t)(n*HH+h))*KT + SS + p)*DD + d] = f2q(pk[src]);
        vt[(((size_t)(n*HH+h))*DD + d)*KT + SS + p] = f2q(pv[src]);
    }
}

// ---------------------------------------------------------------------------
// K1 v2: QKV projection, bf16 MFMA, XCD-swizzled.
// q/k out fp8 [s][d]; V -> transposed fp8 vt[nh][d][k=s].
// ---------------------------------------------------------------------------
__global__ __launch_bounds__(256) void qkv_mfma(
    const float* __restrict__ x, const short* __restrict__ Bqkv,
    uchar* __restrict__ qf, uchar* __restrict__ kf, uchar* __restrict__ vt)
{
    __shared__ short Xs[64*72];
    __shared__ short Ws[192*72];
    const int tid = threadIdx.x;
    const int lin = blockIdx.x;                     // grid 1024 linear
    const int xcd = lin & 7, slot = lin >> 3;       // slot in [0,128)
    const int m0 = (xcd*16 + (slot & 15))*64;
    const int h = slot >> 4;
    const int wave = tid >> 6, lane = tid & 63;
    const int lr = lane & 15, lq = lane >> 4;

    for (int i = tid; i < 1024; i += 256) {
        int r = i >> 4, cg = (i & 15)*4;
        float4 v = *(const float4*)(x + (size_t)(m0+r)*CC + h*64 + cg);
        Xs[r*72+cg+0] = f2s(v.x); Xs[r*72+cg+1] = f2s(v.y);
        Xs[r*72+cg+2] = f2s(v.z); Xs[r*72+cg+3] = f2s(v.w);
    }
    for (int i = tid; i < 3072; i += 256) {
        int r = i >> 4, cg = (i & 15)*4;
        *(short4*)(Ws + r*72 + cg) = *(const short4*)(Bqkv + (size_t)r*64 + cg);
    }
    __syncthreads();

    f32x4 acc[12];
    #pragma unroll
    for (int nt = 0; nt < 12; ++nt) acc[nt] = {0.f,0.f,0.f,0.f};
    #pragma unroll
    for (int ks = 0; ks < 2; ++ks) {
        int ko = ks*32 + lq*8;
        short8 a = *(const short8*)(Xs + (wave*16 + lr)*72 + ko);
        #pragma unroll
        for (int nt = 0; nt < 12; ++nt) {
            short8 b = *(const short8*)(Ws + (nt*16 + lr)*72 + ko);
            acc[nt] = MFMA16(a, b, acc[nt]);
        }
    }
    #pragma unroll
    for (int nt = 0; nt < 12; ++nt) {
        int ep = nt*16 + lr;
        int w = ep >> 6, e = ep & 63;
        #pragma unroll
        for (int reg = 0; reg < 4; ++reg) {
            int m = m0 + wave*16 + lq*4 + reg;
            int n = m >> 10, s = m & 1023;
            float v = acc[nt][reg];
            if (w == 0)      qf[((size_t)(n*HH+h)*SS + s)*DD + e] = f2q(v);
            else if (w == 1) kf[((size_t)(n*HH+h)*KT + s)*DD + e] = f2q(v);
            else             vt[(((size_t)(n*HH+h))*DD + e)*KT + s] = f2q(v);
        }
    }
}

// ---------------------------------------------------------------------------
// K2 v3: energy (RAW, pre-mix), fp8 MFMA NT, XCD-swizzled.
// E layout: [n][q][h][KTE] with KTE=1088 (64B-aligned head rows).
// ---------------------------------------------------------------------------
__device__ __forceinline__ void en_loadK(const uchar* __restrict__ kf,
    int nh, int kt, int tid, uint2* rk)
{
    #pragma unroll
    for (int j = 0; j < 2; ++j) {
        int i = tid + j*256;
        int r = i >> 3, c8 = (i & 7)*8;
        int kcol = kt*64 + r;
        uint2 v = {0u, 0u};
        if (kcol < KT)
            v = *(const uint2*)(kf + ((size_t)nh*KT + kcol)*DD + c8);
        rk[j] = v;
    }
}

__global__ __launch_bounds__(256) void energy_mfma8(
    const uchar* __restrict__ qf, const uchar* __restrict__ kf,
    uchar* __restrict__ E)
{
    __shared__ uchar Qs[64*72];
    __shared__ uchar Ks[64*72];
    const int tid = threadIdx.x;
    const int lin = blockIdx.x + 16*blockIdx.y;     // grid (16, 64)
    const int xcd = lin & 7, slot = lin >> 3;       // slot in [0,128)
    const int nh = xcd*8 + (slot & 7);
    const int mt = slot >> 3;
    const int wave = tid >> 6, lane = tid & 63;
    const int lr = lane & 15, lq = lane >> 4;
    const int n = nh >> 3, h = nh & 7;

    #pragma unroll
    for (int j = 0; j < 2; ++j) {
        int i = tid + j*256;
        int r = i >> 3, c8 = (i & 7)*8;
        *(uint2*)(Qs + r*72 + c8) =
            *(const uint2*)(qf + ((size_t)nh*SS + mt*64 + r)*DD + c8);
    }

    uint2 rk[2];
    en_loadK(kf, nh, 0, tid, rk);

    for (int kt = 0; kt < 17; ++kt) {
        if (kt) __syncthreads();
        #pragma unroll
        for (int j = 0; j < 2; ++j) {
            int i = tid + j*256;
            *(uint2*)(Ks + (i >> 3)*72 + (i & 7)*8) = rk[j];
        }
        __syncthreads();
        if (kt + 1 < 17) en_loadK(kf, nh, kt+1, tid, rk);

        f32x4 acc[4];
        #pragma unroll
        for (int nt = 0; nt < 4; ++nt) acc[nt] = {0.f,0.f,0.f,0.f};
        #pragma unroll
        for (int ks = 0; ks < 2; ++ks) {
            int ko = ks*32 + lq*8;
            long a = *(const long*)(Qs + (wave*16 + lr)*72 + ko);
            #pragma unroll
            for (int nt = 0; nt < 4; ++nt) {
                long b = *(const long*)(Ks + (nt*16 + lr)*72 + ko);
                acc[nt] = MFMAF8(a, b, acc[nt]);
            }
        }
        #pragma unroll
        for (int nt = 0; nt < 4; ++nt) {
            int kcol = kt*64 + nt*16 + lr;
            if (kcol >= KT) continue;
            #pragma unroll
            for (int reg = 0; reg < 4; ++reg) {
                int q = mt*64 + wave*16 + lq*4 + reg;
                E[(((size_t)(n*SS + q))*HH + h)*KTE + kcol] = f2q(acc[nt][reg]);
            }
        }
    }
}

// ---------------------------------------------------------------------------
// K3+K4 fused: pv_fused v2 — per block: (n, 16 q-rows) x all 8 heads.
// v2 register diet (v1 spilled -> 430 MB scratch writes):
//  - NO V LDS staging: V is L2-resident (532 KB/n); MFMA B-fragments loaded
//    directly from global vt into 16 operand regs at the top of each k-tile.
//  - scalar row sums (float[8], not f32x4[8]).
//  - shift/dist folded into accumulator init.
// Only Ps (9 KB) lives in LDS. Unnormalized-shifted p fp8; epilogue divide.
// Grid dim3(8,64): blockIdx.x = n == XCD -> vt stays in that XCD's L2.
// ---------------------------------------------------------------------------
__device__ __forceinline__ void pvf_loadE(const uchar* __restrict__ Eb,
    int kt, int k4, uint* rE)
{
    int kb = kt*64 + k4;
    if (kb < KT) {
        #pragma unroll
        for (int g = 0; g < 8; ++g)
            rE[g] = *(const uint*)(Eb + (size_t)g*KTE + kb);
    } else {
        #pragma unroll
        for (int g = 0; g < 8; ++g) rE[g] = 0u;
    }
}

__global__ __launch_bounds__(256, 2) void pv_fused(
    const uchar* __restrict__ E, const uchar* __restrict__ vt,
    const int* __restrict__ mask, const float* __restrict__ th_pre,
    short* __restrict__ AO)
{
    __shared__ uchar Ps[8*16*72];        //  9 KB: p fp8, [h][q16][72]
    __shared__ float Sred[16][8];        // 1/rowsum per (q,h)
    const int tid  = threadIdx.x;
    const int n    = blockIdx.x;         // 8  (== XCD)
    const int ql0  = blockIdx.y * 16;    // 64 q-tiles
    const int wave = tid >> 6, lane = tid & 63;
    const int lr = lane & 15, lq = lane >> 4;
    const int q_l = tid >> 4, kq = tid & 15, k4 = kq*4;
    const int q = ql0 + q_l;

    // scaled talking-heads weights + mixed ALiBi slopes -> SGPRs
    const float sc = 0.044194173824159216f * 1.4426950408889634f; // 1/sqrt(C)*log2e
    float thp_s[64], slmix_s[8], shift_s[8];
    {
        const float slv[8] = {0.5f,0.25f,0.125f,0.0625f,
                              0.03125f,0.015625f,0.0078125f,0.00390625f};
        const float maxd = (float)((q > SS-1-q) ? q : (SS-1-q));
        #pragma unroll
        for (int h = 0; h < 8; ++h) {
            float sm = 0.f;
            #pragma unroll
            for (int g = 0; g < 8; ++g) {
                float v = rfl(th_pre[h*8+g] * sc);
                thp_s[h*8+g] = v;
                sm += v * slv[g];
            }
            slmix_s[h] = rfl(sm);
            shift_s[h] = fmaxf(0.f, -slmix_s[h] * maxd);   // per-thread (q)
        }
    }

    const uchar* Eb  = E  + ((size_t)(n*SS + q))*HH*KTE;  // head-0 row, this q
    const uchar* vtb = vt + (size_t)n*HH*DD*KT;
    const int*  mrow = mask + (size_t)n*SS*SS + (size_t)q*SS;
    // this wave's 2 heads' V base rows (d-major, stride KT)
    const uchar* Vh0 = vtb + (size_t)(wave*2 + 0)*DD*KT;
    const uchar* Vh1 = vtb + (size_t)(wave*2 + 1)*DD*KT;

    uint rE[8]; int4 rm;
    pvf_loadE(Eb, 0, k4, rE);
    rm = *(const int4*)(mrow + k4);

    float sums[8];
    #pragma unroll
    for (int h = 0; h < 8; ++h) sums[h] = 0.f;
    f32x4 acc[2][4];
    #pragma unroll
    for (int i = 0; i < 2; ++i)
        #pragma unroll
        for (int j = 0; j < 4; ++j) acc[i][j] = {0.f,0.f,0.f,0.f};

    for (int kt = 0; kt < 17; ++kt) {
        // ---- issue this tile's B (V) operand loads early: L2-hit latency
        //      hides under the premix VALU below.
        long bv0[2][4], bv1[2][4];
        #pragma unroll
        for (int ks = 0; ks < 2; ++ks) {
            int ko = kt*64 + ks*32 + lq*8;
            #pragma unroll
            for (int nt = 0; nt < 4; ++nt) {
                size_t ro = (size_t)(nt*16 + lr)*KT + ko;
                bv0[ks][nt] = *(const long*)(Vh0 + ro);
                bv1[ks][nt] = *(const long*)(Vh1 + ro);
            }
        }

        // ---- premix + shifted softmax numerator (registers only)
        uint pb[8];
        {
            const bool body = (kt < 16);
            const bool pvalid = (kt*64 + k4) < KT;   // tail tile: 16 valid cols
            float kb = (float)(kt*64 + k4), qv = (float)q;
            f32x4 dist;
            dist.x = fabsf(qv - kb);       dist.y = fabsf(qv - kb - 1.f);
            dist.z = fabsf(qv - kb - 2.f); dist.w = fabsf(qv - kb - 3.f);

            f32x4 t[8];
            #pragma unroll
            for (int h = 0; h < 8; ++h) {
                if (body) {
                    float sl = slmix_s[h], shf = shift_s[h];
                    t[h].x = -dist.x*sl - shf; t[h].y = -dist.y*sl - shf;
                    t[h].z = -dist.z*sl - shf; t[h].w = -dist.w*sl - shf;
                } else {
                    float shf = shift_s[h];
                    t[h] = {-shf,-shf,-shf,-shf};
                }
            }
            #pragma unroll
            for (int g = 0; g < 8; ++g) {
                f32x2 lo = __builtin_amdgcn_cvt_pk_f32_fp8((int)rE[g], false);
                f32x2 hi = __builtin_amdgcn_cvt_pk_f32_fp8((int)rE[g], true);
                f32x4 a; a.x = lo.x; a.y = lo.y; a.z = hi.x; a.w = hi.y;
                #pragma unroll
                for (int h = 0; h < 8; ++h) t[h] += a * thp_s[h*8+g];
            }
            #pragma unroll
            for (int h = 0; h < 8; ++h) {
                f32x4 e;
                if (body) {
                    e.x = (rm.x == 0) ? 0.f : exp2f(t[h].x);
                    e.y = (rm.y == 0) ? 0.f : exp2f(t[h].y);
                    e.z = (rm.z == 0) ? 0.f : exp2f(t[h].z);
                    e.w = (rm.w == 0) ? 0.f : exp2f(t[h].w);
                } else if (pvalid) {       // persistent keys: no bias, no mask
                    e.x = exp2f(t[h].x); e.y = exp2f(t[h].y);
                    e.z = exp2f(t[h].z); e.w = exp2f(t[h].w);
                } else {
                    e = {0.f,0.f,0.f,0.f};
                }
                sums[h] += (e.x + e.y) + (e.z + e.w);
                int p0 = __builtin_amdgcn_cvt_pk_fp8_f32(e.x, e.y, 0, false);
                p0 = __builtin_amdgcn_cvt_pk_fp8_f32(e.z, e.w, p0, true);
                pb[h] = (uint)p0;
            }
        }
        __syncthreads();                   // prev MFMA done reading Ps
        #pragma unroll
        for (int h = 0; h < 8; ++h)
            *(uint*)(Ps + h*1152 + q_l*72 + k4) = pb[h];
        __syncthreads();
        if (kt + 1 < 17) {                 // prefetch next E tile + mask
            pvf_loadE(Eb, kt+1, k4, rE);
            if (kt + 1 < 16) rm = *(const int4*)(mrow + (kt+1)*64 + k4);
        }
        #pragma unroll
        for (int h2 = 0; h2 < 2; ++h2) {   // wave owns heads wave*2, wave*2+1
            const uchar* Ph = Ps + (wave*2 + h2)*1152;
            #pragma unroll
            for (int ks = 0; ks < 2; ++ks) {
                int ko = ks*32 + lq*8;
                long av = *(const long*)(Ph + lr*72 + ko);
                #pragma unroll
                for (int nt = 0; nt < 4; ++nt) {
                    long bvv = h2 ? bv1[ks][nt] : bv0[ks][nt];
                    acc[h2][nt] = MFMAF8(av, bvv, acc[h2][nt]);
                }
            }
        }
    }

    // ---- row sums: 16-lane shuffle reduce -> 1/sum in LDS
    #pragma unroll
    for (int h = 0; h < 8; ++h) {
        float s = sums[h];
        s += __shfl_xor(s, 1); s += __shfl_xor(s, 2);
        s += __shfl_xor(s, 4); s += __shfl_xor(s, 8);
        if (kq == 0) Sred[q_l][h] = 1.0f / s;
    }
    __syncthreads();

    // ---- normalize + store AO (bf16)
    #pragma unroll
    for (int h2 = 0; h2 < 2; ++h2) {
        int h = wave*2 + h2;
        #pragma unroll
        for (int reg = 0; reg < 4; ++reg) {
            float inv = Sred[lq*4 + reg][h];
            int qg = ql0 + lq*4 + reg;
            #pragma unroll
            for (int nt = 0; nt < 4; ++nt) {
                int d = nt*16 + lr;
                AO[((size_t)(n*SS) + qg)*CC + h*64 + d] =
                    f2s(acc[h2][nt][reg] * inv);
            }
        }
    }
}

// ---------------------------------------------------------------------------
// K5: fc (th_post folded into weights), bf16 MFMA, 64x64, XCD-swizzled.
// ---------------------------------------------------------------------------
__device__ __forceinline__ void g_load4(const short* __restrict__ src,
    size_t rowstride, int row0, int col0, int tid, short4* r)
{
    #pragma unroll
    for (int j = 0; j < 4; ++j) {
        int i = tid + j*256;
        int rr = i >> 4, cg = (i & 15)*4;
        r[j] = *(const short4*)(src + (size_t)(row0 + rr)*rowstride + col0 + cg);
    }
}
__device__ __forceinline__ void lds_store4(short* __restrict__ dst,
    int tid, const short4* r)
{
    #pragma unroll
    for (int j = 0; j < 4; ++j) {
        int i = tid + j*256;
        *(short4*)(dst + (i >> 4)*72 + (i & 15)*4) = r[j];
    }
}

__global__ __launch_bounds__(256) void fc_mfma(
    const short* __restrict__ A, const short* __restrict__ Bt,
    const float* __restrict__ bias, const float* __restrict__ x,
    short* __restrict__ out, uchar* __restrict__ out8)
{
    __shared__ short As[64*72];
    __shared__ short Bs[64*72];
    const int tid = threadIdx.x;
    const int lin = blockIdx.x + 8*blockIdx.y;      // grid (8,128)
    const int xcd = lin & 7, slot = lin >> 3;
    const int m0 = (xcd*16 + (slot & 15))*64;
    const int n0 = (slot >> 4)*64;
    const int wave = tid >> 6, lane = tid & 63;
    const int lr = lane & 15, lq = lane >> 4;

    short4 ra[4], rb[4];
    g_load4(A, CC, m0, 0, tid, ra);
    g_load4(Bt, CC, n0, 0, tid, rb);

    f32x4 acc[4];
    #pragma unroll
    for (int nt = 0; nt < 4; ++nt) acc[nt] = {0.f,0.f,0.f,0.f};

    for (int kt = 0; kt < CC; kt += 64) {
        if (kt) __syncthreads();
        lds_store4(As, tid, ra);
        lds_store4(Bs, tid, rb);
        __syncthreads();
        if (kt + 64 < CC) {
            g_load4(A, CC, m0, kt+64, tid, ra);
            g_load4(Bt, CC, n0, kt+64, tid, rb);
        }
        #pragma unroll
        for (int ks = 0; ks < 2; ++ks) {
            int ko = ks*32 + lq*8;
            short8 a = *(const short8*)(As + (wave*16 + lr)*72 + ko);
            #pragma unroll
            for (int nt = 0; nt < 4; ++nt) {
                short8 b = *(const short8*)(Bs + (nt*16 + lr)*72 + ko);
                acc[nt] = MFMA16(a, b, acc[nt]);
            }
        }
    }
    #pragma unroll
    for (int nt = 0; nt < 4; ++nt) {
        int nn = n0 + nt*16 + lr;
        #pragma unroll
        for (int reg = 0; reg < 4; ++reg) {
            int m = m0 + wave*16 + lq*4 + reg;
            float v = acc[nt][reg] + bias[nn] + x[(size_t)m*CC + nn];
            out[(size_t)m*CC + nn]  = f2s(v);
            out8[(size_t)m*CC + nn] = f2q(v);
        }
    }
}

// ---------------------------------------------------------------------------
// K6 v2: causal conv fp8 NT GEMM, BK=128 (12 K-iters), XCD-swizzled.
// ---------------------------------------------------------------------------
__device__ __forceinline__ void conv_loadA8w(const uchar* __restrict__ A,
    int m0, int kt, int tid, uint2* ra)
{
    const int shift = (kt >> 9) - 2;
    const int ci0 = kt & 511;
    #pragma unroll
    for (int j = 0; j < 4; ++j) {
        int i = tid + j*256;
        int rr = i >> 4, c8 = (i & 15)*8;
        int m = m0 + rr;
        int s = m & (SS-1);
        uint2 v = {0u, 0u};
        if (s + shift >= 0)
            v = *(const uint2*)(A + (size_t)(m + shift)*CC + ci0 + c8);
        ra[j] = v;
    }
}
__device__ __forceinline__ void g_load8w(const uchar* __restrict__ src,
    size_t rowstride, int row0, int col0, int tid, uint2* r)
{
    #pragma unroll
    for (int j = 0; j < 4; ++j) {
        int i = tid + j*256;
        int rr = i >> 4, c8 = (i & 15)*8;
        r[j] = *(const uint2*)(src + (size_t)(row0 + rr)*rowstride + col0 + c8);
    }
}
__device__ __forceinline__ void lds_store8w(uchar* __restrict__ dst,
    int tid, const uint2* r)
{
    #pragma unroll
    for (int j = 0; j < 4; ++j) {
        int i = tid + j*256;
        *(uint2*)(dst + (i >> 4)*136 + (i & 15)*8) = r[j];
    }
}

__global__ __launch_bounds__(256) void conv_mfma8(
    const uchar* __restrict__ A, const uchar* __restrict__ Bt,
    const float* __restrict__ bias, uchar* __restrict__ out8,
    short* __restrict__ out16, int f8out)
{
    __shared__ uchar As[64*136];
    __shared__ uchar Bs[64*136];
    const int tid = threadIdx.x;
    const int lin = blockIdx.x + 8*blockIdx.y;      // grid (8,128)
    const int xcd = lin & 7, slot = lin >> 3;
    const int m0 = (xcd*16 + (slot & 15))*64;
    const int n0 = (slot >> 4)*64;
    const int wave = tid >> 6, lane = tid & 63;
    const int lr = lane & 15, lq = lane >> 4;

    uint2 ra[4], rb[4];
    conv_loadA8w(A, m0, 0, tid, ra);
    g_load8w(Bt, 1536, n0, 0, tid, rb);

    f32x4 acc[4];
    #pragma unroll
    for (int nt = 0; nt < 4; ++nt) acc[nt] = {0.f,0.f,0.f,0.f};

    for (int kt = 0; kt < 1536; kt += 128) {
        if (kt) __syncthreads();
        lds_store8w(As, tid, ra);
        lds_store8w(Bs, tid, rb);
        __syncthreads();
        if (kt + 128 < 1536) {
            conv_loadA8w(A, m0, kt+128, tid, ra);
            g_load8w(Bt, 1536, n0, kt+128, tid, rb);
        }
        #pragma unroll
        for (int ks = 0; ks < 4; ++ks) {
            int ko = ks*32 + lq*8;
            long a = *(const long*)(As + (wave*16 + lr)*136 + ko);
            #pragma unroll
            for (int nt = 0; nt < 4; ++nt) {
                long b = *(const long*)(Bs + (nt*16 + lr)*136 + ko);
                acc[nt] = MFMAF8(a, b, acc[nt]);
            }
        }
    }
    #pragma unroll
    for (int nt = 0; nt < 4; ++nt) {
        int nn = n0 + nt*16 + lr;
        #pragma unroll
        for (int reg = 0; reg < 4; ++reg) {
            int m = m0 + wave*16 + lq*4 + reg;
            float v = fmaxf(acc[nt][reg]*0.0625f + bias[nn], 0.f);
            if (f8out) out8[(size_t)m*CC + nn]  = f2q(v);
            else       out16[(size_t)m*CC + nn] = f2s(v);
        }
    }
}

// ---------------------------------------------------------------------------
// K7: out = LN(relu(c2 + xres) masked) * g + b.  4 rows per block.
// ---------------------------------------------------------------------------
__global__ __launch_bounds__(256) void final_kernel(
    const short* __restrict__ c2, const short* __restrict__ xres,
    const int* __restrict__ mask, const float* __restrict__ g,
    const float* __restrict__ b, float* __restrict__ out)
{
    __shared__ float red[256];
    const int tid = threadIdx.x;
    const int m0 = blockIdx.x * 4;
    const int c0 = tid*2;
    const float2 gg = *(const float2*)(g + c0);
    const float2 bb = *(const float2*)(b + c0);

    for (int rr = 0; rr < 4; ++rr) {
        const int m = m0 + rr;
        const int n = m >> 10, s = m & 1023;
        const int mk = mask[(size_t)n*SS*SS + (size_t)s*SS];

        short2 ca = *(const short2*)(c2 + (size_t)m*CC + c0);
        short2 xa = *(const short2*)(xres + (size_t)m*CC + c0);
        float v0 = fmaxf(s2f(ca.x) + s2f(xa.x), 0.f);
        float v1 = fmaxf(s2f(ca.y) + s2f(xa.y), 0.f);
        if (mk == 0) { v0 = 0.f; v1 = 0.f; }

        red[tid] = v0 + v1;
        __syncthreads();
        for (int off = 128; off > 0; off >>= 1) {
            if (tid < off) red[tid] += red[tid + off];
            __syncthreads();
        }
        float mu = red[0] * (1.0f/512.0f);
        __syncthreads();
        float d0 = v0 - mu, d1 = v1 - mu;
        red[tid] = d0*d0 + d1*d1;
        __syncthreads();
        for (int off = 128; off > 0; off >>= 1) {
            if (tid < off) red[tid] += red[tid + off];
            __syncthreads();
        }
        float rstd = rsqrtf(red[0] * (1.0f/512.0f) + 1e-5f);
        float2 o;
        o.x = d0*rstd*gg.x + bb.x;
        o.y = d1*rstd*gg.y + bb.y;
        *(float2*)(out + (size_t)m*CC + c0) = o;
        __syncthreads();                     // red reuse next row
    }
}

// ---------------------------------------------------------------------------
extern "C" void kernel_launch(void* const* d_in, const int* in_sizes, int n_in,
                              void* d_out, int out_size, void* d_ws, size_t ws_size,
                              hipStream_t stream)
{
    const float* x      = (const float*)d_in[0];
    const int*   mask   = (const int*)  d_in[1];
    const float* Wq     = (const float*)d_in[2];
    const float* Wk     = (const float*)d_in[3];
    const float* Wv     = (const float*)d_in[4];
    const float* pk     = (const float*)d_in[5];
    const float* pv     = (const float*)d_in[6];
    const float* th_pre = (const float*)d_in[7];
    const float* th_post= (const float*)d_in[8];
    const float* fc_w   = (const float*)d_in[9];
    const float* fc_b   = (const float*)d_in[10];
    const float* c1w    = (const float*)d_in[11];
    const float* c1b    = (const float*)d_in[12];
    const float* c2w    = (const float*)d_in[13];
    const float* c2b    = (const float*)d_in[14];
    const float* lng    = (const float*)d_in[15];
    const float* lnb    = (const float*)d_in[16];
    float* out = (float*)d_out;
    (void)in_sizes; (void)n_in; (void)out_size; (void)ws_size;

    char* ws = (char*)d_ws;
    const size_t SZ_Q  = (size_t)BN*HH*SS*DD;      //  4.19 MB (fp8)
    const size_t SZ_K  = (size_t)BN*HH*KT*DD;      //  4.26 MB (fp8)
    const size_t SZ_VT = (size_t)BN*HH*DD*KT;      //  4.26 MB (fp8)
    const size_t SZ_E  = (size_t)BN*SS*HH*KTE;     // 71.3 MB (fp8, raw energy)
    const size_t SZ_A  = (size_t)BN*SS*CC*2;       //  8.39 MB (bf16)
    const size_t SZ_A8 = (size_t)BN*SS*CC;         //  4.19 MB (fp8)

    uchar* qf  = (uchar*)(ws);
    uchar* kf  = (uchar*)(ws + SZ_Q);
    uchar* vt  = (uchar*)(ws + SZ_Q + SZ_K);
    uchar* E   = (uchar*)(ws + SZ_Q + SZ_K + SZ_VT);
    short* AO  = (short*)(ws + SZ_Q + SZ_K + SZ_VT + SZ_E);
    char*  wend = ws + SZ_Q + SZ_K + SZ_VT + SZ_E + SZ_A;
    short* Bfc = (short*)(wend);
    uchar* Bc1 = (uchar*)(wend + 512*512*2);
    uchar* Bc2 = (uchar*)(wend + 512*512*2 + 512*1536);
    short* Bqkv= (short*)(wend + 512*512*2 + 2*512*1536);
    uchar* xres8 = (uchar*)(wend + 512*512*2 + 2*512*1536 + 3*64*64*2);
    short* c2buf = (short*)(wend + 512*512*2 + 2*512*1536 + 3*64*64*2 + SZ_A8);
    // Aliases (dead regions): xres(bf16) over qf+kf (dead after energy);
    // h1(fp8) over E (dead after pv_fused).
    short* xres = (short*)(ws);
    uchar* h18  = (uchar*)E;
    // total ws ~= 106 MB (ws_size >= 256 MiB)

    {
        int total = 512*512 + 2*512*1536 + 3*64*64 + BN*HH*PP*DD;
        prep_kernel<<<(total + 255)/256, 256, 0, stream>>>(
            fc_w, c1w, c2w, Wq, Wk, Wv, th_post, pk, pv,
            Bfc, Bc1, Bc2, Bqkv, kf, vt);
    }
    qkv_mfma<<<BN*SS/64*HH, 256, 0, stream>>>(x, Bqkv, qf, kf, vt);

    energy_mfma8<<<dim3(16, 64), 256, 0, stream>>>(qf, kf, E);
    pv_fused<<<dim3(8, 64), 256, 0, stream>>>(E, vt, mask, th_pre, AO);

    fc_mfma<<<dim3(8, 128), 256, 0, stream>>>(AO, Bfc, fc_b, x, xres, xres8);
    conv_mfma8<<<dim3(8, 128), 256, 0, stream>>>(xres8, Bc1, c1b, h18, (short*)nullptr, 1);
    conv_mfma8<<<dim3(8, 128), 256, 0, stream>>>(h18, Bc2, c2b, (uchar*)nullptr, c2buf, 0);
    final_kernel<<<BN*SS/4, 256, 0, stream>>>(c2buf, xres, mask, lng, lnb, out);
}

// Round 4
// 299.884 us; speedup vs baseline: 2.6041x; 1.9448x over previous
//
#include <hip/hip_runtime.h>
#include <hip/hip_bf16.h>

#define BN 8
#define SS 1024
#define CC 512
#define HH 8
#define DD 64
#define PP 16
#define KT 1040
#define KTE 1088   // E head-row stride, padded to 64B multiple

typedef __hip_bfloat16 bf16;
typedef unsigned char uchar;
typedef unsigned short ushort;
typedef unsigned int uint;
typedef __attribute__((ext_vector_type(8))) short short8;
typedef __attribute__((ext_vector_type(4))) float f32x4;
typedef __attribute__((ext_vector_type(2))) float f32x2;

__device__ __forceinline__ short f2s(float v){ bf16 b = __float2bfloat16(v); return *(short*)&b; }
__device__ __forceinline__ float s2f(short s){ bf16 b; *(short*)&b = s; return __bfloat162float(b); }
__device__ __forceinline__ uchar f2q(float v){          // f32 -> fp8 e4m3 byte
    return (uchar)__builtin_amdgcn_cvt_pk_fp8_f32(v, v, 0, false);
}
__device__ __forceinline__ float rfl(float x){          // force to SGPR
    return __int_as_float(__builtin_amdgcn_readfirstlane(__float_as_int(x)));
}

#define MFMA16(a,b,c)  __builtin_amdgcn_mfma_f32_16x16x32_bf16(a,b,c,0,0,0)
#define MFMAF8(a,b,c)  __builtin_amdgcn_mfma_f32_16x16x32_fp8_fp8(a,b,c,0,0,0)

// ---------------------------------------------------------------------------
// P0: weight pre-conversion + persistent-token tails.
// ---------------------------------------------------------------------------
__global__ __launch_bounds__(256) void prep_kernel(
    const float* __restrict__ fc_w, const float* __restrict__ c1w,
    const float* __restrict__ c2w, const float* __restrict__ Wq,
    const float* __restrict__ Wk, const float* __restrict__ Wv,
    const float* __restrict__ th_post,
    const float* __restrict__ pk, const float* __restrict__ pv,
    short* __restrict__ Bfc, uchar* __restrict__ Bc1,
    uchar* __restrict__ Bc2, short* __restrict__ Bqkv,
    uchar* __restrict__ kf, uchar* __restrict__ vt)
{
    int i = blockIdx.x*256 + threadIdx.x;
    const int NFC = 512*512, NCV = 512*1536, NQ = 3*64*64, NP = BN*HH*PP*DD;
    if (i < NFC) {
        int c = i >> 9, r = i & 511;
        int g = r >> 6, d = r & 63;
        float s = 0.f;
        #pragma unroll
        for (int h = 0; h < 8; ++h)
            s += fc_w[(size_t)c*512 + h*64 + d] * th_post[h*8 + g];
        Bfc[i] = f2s(s);
        return;
    }
    i -= NFC;
    if (i < NCV) {
        int o = i/1536, r = i%1536, dk = r>>9, ci = r&511;
        Bc1[i] = f2q(c1w[(o*512+ci)*3+dk] * 16.f); return;
    }
    i -= NCV;
    if (i < NCV) {
        int o = i/1536, r = i%1536, dk = r>>9, ci = r&511;
        Bc2[i] = f2q(c2w[(o*512+ci)*3+dk] * 16.f); return;
    }
    i -= NCV;
    if (i < NQ) {
        int w = i >> 12, rest = i & 4095;
        const float* W = (w==0)?Wq:(w==1)?Wk:Wv;
        Bqkv[i] = f2s(W[((rest>>6)&63)*64 + (rest&63)]);
        return;
    }
    i -= NQ;
    if (i < NP) {
        int d = i & 63, p = (i >> 6) & 15, h = (i >> 10) & 7, n = i >> 13;
        size_t src = ((size_t)p*HH + h)*DD + d;
        kf[(((size_t)(n*HH+h))*KT + SS + p)*DD + d] = f2q(pk[src]);
        vt[(((size_t)(n*HH+h))*DD + d)*KT + SS + p] = f2q(pv[src]);
    }
}

// ---------------------------------------------------------------------------
// K1 v2: QKV projection, bf16 MFMA, XCD-swizzled.
// q/k out fp8 [s][d]; V -> transposed fp8 vt[nh][d][k=s].
// ---------------------------------------------------------------------------
__global__ __launch_bounds__(256) void qkv_mfma(
    const float* __restrict__ x, const short* __restrict__ Bqkv,
    uchar* __restrict__ qf, uchar* __restrict__ kf, uchar* __restrict__ vt)
{
    __shared__ short Xs[64*72];
    __shared__ short Ws[192*72];
    const int tid = threadIdx.x;
    const int lin = blockIdx.x;                     // grid 1024 linear
    const int xcd = lin & 7, slot = lin >> 3;       // slot in [0,128)
    const int m0 = (xcd*16 + (slot & 15))*64;
    const int h = slot >> 4;
    const int wave = tid >> 6, lane = tid & 63;
    const int lr = lane & 15, lq = lane >> 4;

    for (int i = tid; i < 1024; i += 256) {
        int r = i >> 4, cg = (i & 15)*4;
        float4 v = *(const float4*)(x + (size_t)(m0+r)*CC + h*64 + cg);
        Xs[r*72+cg+0] = f2s(v.x); Xs[r*72+cg+1] = f2s(v.y);
        Xs[r*72+cg+2] = f2s(v.z); Xs[r*72+cg+3] = f2s(v.w);
    }
    for (int i = tid; i < 3072; i += 256) {
        int r = i >> 4, cg = (i & 15)*4;
        *(short4*)(Ws + r*72 + cg) = *(const short4*)(Bqkv + (size_t)r*64 + cg);
    }
    __syncthreads();

    f32x4 acc[12];
    #pragma unroll
    for (int nt = 0; nt < 12; ++nt) acc[nt] = {0.f,0.f,0.f,0.f};
    #pragma unroll
    for (int ks = 0; ks < 2; ++ks) {
        int ko = ks*32 + lq*8;
        short8 a = *(const short8*)(Xs + (wave*16 + lr)*72 + ko);
        #pragma unroll
        for (int nt = 0; nt < 12; ++nt) {
            short8 b = *(const short8*)(Ws + (nt*16 + lr)*72 + ko);
            acc[nt] = MFMA16(a, b, acc[nt]);
        }
    }
    #pragma unroll
    for (int nt = 0; nt < 12; ++nt) {
        int ep = nt*16 + lr;
        int w = ep >> 6, e = ep & 63;
        #pragma unroll
        for (int reg = 0; reg < 4; ++reg) {
            int m = m0 + wave*16 + lq*4 + reg;
            int n = m >> 10, s = m & 1023;
            float v = acc[nt][reg];
            if (w == 0)      qf[((size_t)(n*HH+h)*SS + s)*DD + e] = f2q(v);
            else if (w == 1) kf[((size_t)(n*HH+h)*KT + s)*DD + e] = f2q(v);
            else             vt[(((size_t)(n*HH+h))*DD + e)*KT + s] = f2q(v);
        }
    }
}

// ---------------------------------------------------------------------------
// K2 v3: energy (RAW, pre-mix), fp8 MFMA NT, XCD-swizzled.
// E layout: [n][q][h][KTE] with KTE=1088 (64B-aligned head rows).
// ---------------------------------------------------------------------------
__device__ __forceinline__ void en_loadK(const uchar* __restrict__ kf,
    int nh, int kt, int tid, uint2* rk)
{
    #pragma unroll
    for (int j = 0; j < 2; ++j) {
        int i = tid + j*256;
        int r = i >> 3, c8 = (i & 7)*8;
        int kcol = kt*64 + r;
        uint2 v = {0u, 0u};
        if (kcol < KT)
            v = *(const uint2*)(kf + ((size_t)nh*KT + kcol)*DD + c8);
        rk[j] = v;
    }
}

__global__ __launch_bounds__(256) void energy_mfma8(
    const uchar* __restrict__ qf, const uchar* __restrict__ kf,
    uchar* __restrict__ E)
{
    __shared__ uchar Qs[64*72];
    __shared__ uchar Ks[64*72];
    const int tid = threadIdx.x;
    const int lin = blockIdx.x + 16*blockIdx.y;     // grid (16, 64)
    const int xcd = lin & 7, slot = lin >> 3;       // slot in [0,128)
    const int nh = xcd*8 + (slot & 7);
    const int mt = slot >> 3;
    const int wave = tid >> 6, lane = tid & 63;
    const int lr = lane & 15, lq = lane >> 4;
    const int n = nh >> 3, h = nh & 7;

    #pragma unroll
    for (int j = 0; j < 2; ++j) {
        int i = tid + j*256;
        int r = i >> 3, c8 = (i & 7)*8;
        *(uint2*)(Qs + r*72 + c8) =
            *(const uint2*)(qf + ((size_t)nh*SS + mt*64 + r)*DD + c8);
    }

    uint2 rk[2];
    en_loadK(kf, nh, 0, tid, rk);

    for (int kt = 0; kt < 17; ++kt) {
        if (kt) __syncthreads();
        #pragma unroll
        for (int j = 0; j < 2; ++j) {
            int i = tid + j*256;
            *(uint2*)(Ks + (i >> 3)*72 + (i & 7)*8) = rk[j];
        }
        __syncthreads();
        if (kt + 1 < 17) en_loadK(kf, nh, kt+1, tid, rk);

        f32x4 acc[4];
        #pragma unroll
        for (int nt = 0; nt < 4; ++nt) acc[nt] = {0.f,0.f,0.f,0.f};
        #pragma unroll
        for (int ks = 0; ks < 2; ++ks) {
            int ko = ks*32 + lq*8;
            long a = *(const long*)(Qs + (wave*16 + lr)*72 + ko);
            #pragma unroll
            for (int nt = 0; nt < 4; ++nt) {
                long b = *(const long*)(Ks + (nt*16 + lr)*72 + ko);
                acc[nt] = MFMAF8(a, b, acc[nt]);
            }
        }
        #pragma unroll
        for (int nt = 0; nt < 4; ++nt) {
            int kcol = kt*64 + nt*16 + lr;
            if (kcol >= KT) continue;
            #pragma unroll
            for (int reg = 0; reg < 4; ++reg) {
                int q = mt*64 + wave*16 + lq*4 + reg;
                E[(((size_t)(n*SS + q))*HH + h)*KTE + kcol] = f2q(acc[nt][reg]);
            }
        }
    }
}

// ---------------------------------------------------------------------------
// K3+K4 fused: pv_fused v3 — wave == head-pair; NO barriers, NO shared thp.
// v2 failed: thp_s[64] couldn't fit the SGPR file -> scratch, re-read 64x per
// thread-tile (~570 MB HBM); t[8]+bv+acc > 128 VGPR -> more spill.
// v3: wave w premixes ONLY its 2 MFMA heads (16 SGPR weights), over all
// 16q x 64k (same total VALU). Raw E/mask read redundantly by 4 waves (L1).
// Waves fully independent: each writes/reads only its own Ps slice ->
// zero __syncthreads; same-wave LDS ordering via compiler lgkmcnt.
// Per-thread peak ~110 VGPR -> fits 128, no spill.
// Grid dim3(8,64): blockIdx.x = n == XCD -> vt L2-resident.
// ---------------------------------------------------------------------------
__global__ __launch_bounds__(256, 2) void pv_fused(
    const uchar* __restrict__ E, const uchar* __restrict__ vt,
    const int* __restrict__ mask, const float* __restrict__ th_pre,
    short* __restrict__ AO)
{
    __shared__ uchar Ps[8*16*72];        //  9 KB: p fp8, [h][q16][72]; per-wave slice
    __shared__ float Sred[16][8];        // 1/rowsum per (q,h); per-wave columns
    const int tid  = threadIdx.x;
    const int n    = blockIdx.x;         // 8  (== XCD)
    const int ql0  = blockIdx.y * 16;    // 64 q-tiles
    const int wave = tid >> 6, lane = tid & 63;
    const int lr = lane & 15, lq = lane >> 4;   // MFMA decomposition
    const int q_l = lane >> 2, kc = lane & 3;   // premix decomposition (per wave)
    const int q  = ql0 + q_l;
    const int hb = wave*2;               // this wave's head pair

    // per-wave talking-heads weights (16 SGPRs) + mixed slopes
    const float sc = 0.044194173824159216f * 1.4426950408889634f; // 1/sqrt(C)*log2e
    float tw[2][8], slmix[2], shf[2];
    {
        const float slv[8] = {0.5f,0.25f,0.125f,0.0625f,
                              0.03125f,0.015625f,0.0078125f,0.00390625f};
        const float maxd = (float)((q > SS-1-q) ? q : (SS-1-q));
        #pragma unroll
        for (int j = 0; j < 2; ++j) {
            float sm = 0.f;
            #pragma unroll
            for (int g = 0; g < 8; ++g) {
                float v = rfl(th_pre[(hb+j)*8+g] * sc);
                tw[j][g] = v;
                sm += v * slv[g];
            }
            slmix[j] = rfl(sm);
            shf[j] = fmaxf(0.f, -slmix[j] * maxd);    // per-thread (q) VGPR
        }
    }

    const uchar* Eb  = E  + ((size_t)(n*SS + q))*HH*KTE;  // head-0 row, this q
    const uchar* Vh0 = vt + ((size_t)(n*HH) + hb + 0)*DD*KT;
    const uchar* Vh1 = vt + ((size_t)(n*HH) + hb + 1)*DD*KT;
    const int*  mrow = mask + (size_t)n*SS*SS + (size_t)q*SS;
    uchar* Ps0 = Ps + (hb+0)*1152;
    uchar* Ps1 = Ps + (hb+1)*1152;

    float sums[2] = {0.f, 0.f};
    f32x4 acc[2][4];
    #pragma unroll
    for (int i = 0; i < 2; ++i)
        #pragma unroll
        for (int j = 0; j < 4; ++j) acc[i][j] = {0.f,0.f,0.f,0.f};

    for (int kt = 0; kt < 17; ++kt) {
        const int kb = kt*64;
        // ---- V operands, head hb: issue before premix (L2 latency hides)
        long bva[2][4];
        #pragma unroll
        for (int ks = 0; ks < 2; ++ks)
            #pragma unroll
            for (int nt = 0; nt < 4; ++nt)
                bva[ks][nt] = *(const long*)(Vh0 + (size_t)(nt*16+lr)*KT + kb + ks*32 + lq*8);

        const bool body = (kt < 16);
        // ---- premix this wave's 2 heads: 16 k per thread, 2 subpasses of 8
        #pragma unroll
        for (int s = 0; s < 2; ++s) {
            const int k0 = kb + kc*16 + s*8;         // global k of 8-col group
            const bool valid = (k0 < KT);            // tail: only kc==0 survives
            int4 rmA = {1,1,1,1}, rmB = {1,1,1,1};
            if (body) {
                rmA = *(const int4*)(mrow + k0);
                rmB = *(const int4*)(mrow + k0 + 4);
            }
            f32x4 tA[2], tB[2];
            if (body) {
                const float qv = (float)q, kf0 = (float)k0;
                f32x4 dA, dB;
                dA.x = fabsf(qv-kf0);      dA.y = fabsf(qv-kf0-1.f);
                dA.z = fabsf(qv-kf0-2.f);  dA.w = fabsf(qv-kf0-3.f);
                dB.x = fabsf(qv-kf0-4.f);  dB.y = fabsf(qv-kf0-5.f);
                dB.z = fabsf(qv-kf0-6.f);  dB.w = fabsf(qv-kf0-7.f);
                #pragma unroll
                for (int j = 0; j < 2; ++j) {
                    tA[j] = -dA*slmix[j] - shf[j];
                    tB[j] = -dB*slmix[j] - shf[j];
                }
            } else {
                #pragma unroll
                for (int j = 0; j < 2; ++j) {
                    tA[j] = {-shf[j],-shf[j],-shf[j],-shf[j]};
                    tB[j] = tA[j];
                }
            }
            #pragma unroll
            for (int g = 0; g < 8; ++g) {
                uint2 av = *(const uint2*)(Eb + (size_t)g*KTE + k0);
                f32x2 lo0 = __builtin_amdgcn_cvt_pk_f32_fp8((int)av.x, false);
                f32x2 hi0 = __builtin_amdgcn_cvt_pk_f32_fp8((int)av.x, true);
                f32x2 lo1 = __builtin_amdgcn_cvt_pk_f32_fp8((int)av.y, false);
                f32x2 hi1 = __builtin_amdgcn_cvt_pk_f32_fp8((int)av.y, true);
                f32x4 aA; aA.x=lo0.x; aA.y=lo0.y; aA.z=hi0.x; aA.w=hi0.y;
                f32x4 aB; aB.x=lo1.x; aB.y=lo1.y; aB.z=hi1.x; aB.w=hi1.y;
                #pragma unroll
                for (int j = 0; j < 2; ++j) {
                    tA[j] += aA * tw[j][g];
                    tB[j] += aB * tw[j][g];
                }
            }
            #pragma unroll
            for (int j = 0; j < 2; ++j) {
                f32x4 eA, eB;
                if (body) {
                    eA.x = (rmA.x==0)?0.f:exp2f(tA[j].x);
                    eA.y = (rmA.y==0)?0.f:exp2f(tA[j].y);
                    eA.z = (rmA.z==0)?0.f:exp2f(tA[j].z);
                    eA.w = (rmA.w==0)?0.f:exp2f(tA[j].w);
                    eB.x = (rmB.x==0)?0.f:exp2f(tB[j].x);
                    eB.y = (rmB.y==0)?0.f:exp2f(tB[j].y);
                    eB.z = (rmB.z==0)?0.f:exp2f(tB[j].z);
                    eB.w = (rmB.w==0)?0.f:exp2f(tB[j].w);
                } else if (valid) {      // persistent keys: no bias, no mask
                    eA.x = exp2f(tA[j].x); eA.y = exp2f(tA[j].y);
                    eA.z = exp2f(tA[j].z); eA.w = exp2f(tA[j].w);
                    eB.x = exp2f(tB[j].x); eB.y = exp2f(tB[j].y);
                    eB.z = exp2f(tB[j].z); eB.w = exp2f(tB[j].w);
                } else {
                    eA = {0.f,0.f,0.f,0.f}; eB = {0.f,0.f,0.f,0.f};
                }
                sums[j] += (eA.x+eA.y)+(eA.z+eA.w) + (eB.x+eB.y)+(eB.z+eB.w);
                int p0 = __builtin_amdgcn_cvt_pk_fp8_f32(eA.x, eA.y, 0, false);
                p0 = __builtin_amdgcn_cvt_pk_fp8_f32(eA.z, eA.w, p0, true);
                int p1 = __builtin_amdgcn_cvt_pk_fp8_f32(eB.x, eB.y, 0, false);
                p1 = __builtin_amdgcn_cvt_pk_fp8_f32(eB.z, eB.w, p1, true);
                uint2 pw; pw.x = (uint)p0; pw.y = (uint)p1;
                uchar* dst = (j ? Ps1 : Ps0) + q_l*72 + kc*16 + s*8;
                *(uint2*)dst = pw;
            }
        }

        // ---- V operands, head hb+1 (latency hidden under h0 MFMAs)
        long bvb[2][4];
        #pragma unroll
        for (int ks = 0; ks < 2; ++ks)
            #pragma unroll
            for (int nt = 0; nt < 4; ++nt)
                bvb[ks][nt] = *(const long*)(Vh1 + (size_t)(nt*16+lr)*KT + kb + ks*32 + lq*8);

        // ---- MFMA (same-wave Ps ordering via compiler lgkmcnt; no barriers)
        #pragma unroll
        for (int ks = 0; ks < 2; ++ks) {
            int ko = ks*32 + lq*8;
            long av0 = *(const long*)(Ps0 + lr*72 + ko);
            #pragma unroll
            for (int nt = 0; nt < 4; ++nt)
                acc[0][nt] = MFMAF8(av0, bva[ks][nt], acc[0][nt]);
            long av1 = *(const long*)(Ps1 + lr*72 + ko);
            #pragma unroll
            for (int nt = 0; nt < 4; ++nt)
                acc[1][nt] = MFMAF8(av1, bvb[ks][nt], acc[1][nt]);
        }
    }

    // ---- row sums: reduce over the 4 kc lanes of each q_l -> 1/sum in LDS
    #pragma unroll
    for (int j = 0; j < 2; ++j) {
        float s = sums[j];
        s += __shfl_xor(s, 1); s += __shfl_xor(s, 2);
        if (kc == 0) Sred[q_l][hb+j] = 1.0f / s;
    }
    // (same-wave LDS write->read; compiler inserts lgkmcnt)

    // ---- normalize + store AO (bf16)
    #pragma unroll
    for (int h2 = 0; h2 < 2; ++h2) {
        int h = hb + h2;
        #pragma unroll
        for (int reg = 0; reg < 4; ++reg) {
            float inv = Sred[lq*4 + reg][h];
            int qg = ql0 + lq*4 + reg;
            #pragma unroll
            for (int nt = 0; nt < 4; ++nt) {
                int d = nt*16 + lr;
                AO[((size_t)(n*SS) + qg)*CC + h*64 + d] =
                    f2s(acc[h2][nt][reg] * inv);
            }
        }
    }
}

// ---------------------------------------------------------------------------
// K5: fc (th_post folded into weights), bf16 MFMA, 64x64, XCD-swizzled.
// ---------------------------------------------------------------------------
__device__ __forceinline__ void g_load4(const short* __restrict__ src,
    size_t rowstride, int row0, int col0, int tid, short4* r)
{
    #pragma unroll
    for (int j = 0; j < 4; ++j) {
        int i = tid + j*256;
        int rr = i >> 4, cg = (i & 15)*4;
        r[j] = *(const short4*)(src + (size_t)(row0 + rr)*rowstride + col0 + cg);
    }
}
__device__ __forceinline__ void lds_store4(short* __restrict__ dst,
    int tid, const short4* r)
{
    #pragma unroll
    for (int j = 0; j < 4; ++j) {
        int i = tid + j*256;
        *(short4*)(dst + (i >> 4)*72 + (i & 15)*4) = r[j];
    }
}

__global__ __launch_bounds__(256) void fc_mfma(
    const short* __restrict__ A, const short* __restrict__ Bt,
    const float* __restrict__ bias, const float* __restrict__ x,
    short* __restrict__ out, uchar* __restrict__ out8)
{
    __shared__ short As[64*72];
    __shared__ short Bs[64*72];
    const int tid = threadIdx.x;
    const int lin = blockIdx.x + 8*blockIdx.y;      // grid (8,128)
    const int xcd = lin & 7, slot = lin >> 3;
    const int m0 = (xcd*16 + (slot & 15))*64;
    const int n0 = (slot >> 4)*64;
    const int wave = tid >> 6, lane = tid & 63;
    const int lr = lane & 15, lq = lane >> 4;

    short4 ra[4], rb[4];
    g_load4(A, CC, m0, 0, tid, ra);
    g_load4(Bt, CC, n0, 0, tid, rb);

    f32x4 acc[4];
    #pragma unroll
    for (int nt = 0; nt < 4; ++nt) acc[nt] = {0.f,0.f,0.f,0.f};

    for (int kt = 0; kt < CC; kt += 64) {
        if (kt) __syncthreads();
        lds_store4(As, tid, ra);
        lds_store4(Bs, tid, rb);
        __syncthreads();
        if (kt + 64 < CC) {
            g_load4(A, CC, m0, kt+64, tid, ra);
            g_load4(Bt, CC, n0, kt+64, tid, rb);
        }
        #pragma unroll
        for (int ks = 0; ks < 2; ++ks) {
            int ko = ks*32 + lq*8;
            short8 a = *(const short8*)(As + (wave*16 + lr)*72 + ko);
            #pragma unroll
            for (int nt = 0; nt < 4; ++nt) {
                short8 b = *(const short8*)(Bs + (nt*16 + lr)*72 + ko);
                acc[nt] = MFMA16(a, b, acc[nt]);
            }
        }
    }
    #pragma unroll
    for (int nt = 0; nt < 4; ++nt) {
        int nn = n0 + nt*16 + lr;
        #pragma unroll
        for (int reg = 0; reg < 4; ++reg) {
            int m = m0 + wave*16 + lq*4 + reg;
            float v = acc[nt][reg] + bias[nn] + x[(size_t)m*CC + nn];
            out[(size_t)m*CC + nn]  = f2s(v);
            out8[(size_t)m*CC + nn] = f2q(v);
        }
    }
}

// ---------------------------------------------------------------------------
// K6 v2: causal conv fp8 NT GEMM, BK=128 (12 K-iters), XCD-swizzled.
// ---------------------------------------------------------------------------
__device__ __forceinline__ void conv_loadA8w(const uchar* __restrict__ A,
    int m0, int kt, int tid, uint2* ra)
{
    const int shift = (kt >> 9) - 2;
    const int ci0 = kt & 511;
    #pragma unroll
    for (int j = 0; j < 4; ++j) {
        int i = tid + j*256;
        int rr = i >> 4, c8 = (i & 15)*8;
        int m = m0 + rr;
        int s = m & (SS-1);
        uint2 v = {0u, 0u};
        if (s + shift >= 0)
            v = *(const uint2*)(A + (size_t)(m + shift)*CC + ci0 + c8);
        ra[j] = v;
    }
}
__device__ __forceinline__ void g_load8w(const uchar* __restrict__ src,
    size_t rowstride, int row0, int col0, int tid, uint2* r)
{
    #pragma unroll
    for (int j = 0; j < 4; ++j) {
        int i = tid + j*256;
        int rr = i >> 4, c8 = (i & 15)*8;
        r[j] = *(const uint2*)(src + (size_t)(row0 + rr)*rowstride + col0 + c8);
    }
}
__device__ __forceinline__ void lds_store8w(uchar* __restrict__ dst,
    int tid, const uint2* r)
{
    #pragma unroll
    for (int j = 0; j < 4; ++j) {
        int i = tid + j*256;
        *(uint2*)(dst + (i >> 4)*136 + (i & 15)*8) = r[j];
    }
}

__global__ __launch_bounds__(256) void conv_mfma8(
    const uchar* __restrict__ A, const uchar* __restrict__ Bt,
    const float* __restrict__ bias, uchar* __restrict__ out8,
    short* __restrict__ out16, int f8out)
{
    __shared__ uchar As[64*136];
    __shared__ uchar Bs[64*136];
    const int tid = threadIdx.x;
    const int lin = blockIdx.x + 8*blockIdx.y;      // grid (8,128)
    const int xcd = lin & 7, slot = lin >> 3;
    const int m0 = (xcd*16 + (slot & 15))*64;
    const int n0 = (slot >> 4)*64;
    const int wave = tid >> 6, lane = tid & 63;
    const int lr = lane & 15, lq = lane >> 4;

    uint2 ra[4], rb[4];
    conv_loadA8w(A, m0, 0, tid, ra);
    g_load8w(Bt, 1536, n0, 0, tid, rb);

    f32x4 acc[4];
    #pragma unroll
    for (int nt = 0; nt < 4; ++nt) acc[nt] = {0.f,0.f,0.f,0.f};

    for (int kt = 0; kt < 1536; kt += 128) {
        if (kt) __syncthreads();
        lds_store8w(As, tid, ra);
        lds_store8w(Bs, tid, rb);
        __syncthreads();
        if (kt + 128 < 1536) {
            conv_loadA8w(A, m0, kt+128, tid, ra);
            g_load8w(Bt, 1536, n0, kt+128, tid, rb);
        }
        #pragma unroll
        for (int ks = 0; ks < 4; ++ks) {
            int ko = ks*32 + lq*8;
            long a = *(const long*)(As + (wave*16 + lr)*136 + ko);
            #pragma unroll
            for (int nt = 0; nt < 4; ++nt) {
                long b = *(const long*)(Bs + (nt*16 + lr)*136 + ko);
                acc[nt] = MFMAF8(a, b, acc[nt]);
            }
        }
    }
    #pragma unroll
    for (int nt = 0; nt < 4; ++nt) {
        int nn = n0 + nt*16 + lr;
        #pragma unroll
        for (int reg = 0; reg < 4; ++reg) {
            int m = m0 + wave*16 + lq*4 + reg;
            float v = fmaxf(acc[nt][reg]*0.0625f + bias[nn], 0.f);
            if (f8out) out8[(size_t)m*CC + nn]  = f2q(v);
            else       out16[(size_t)m*CC + nn] = f2s(v);
        }
    }
}

// ---------------------------------------------------------------------------
// K7: out = LN(relu(c2 + xres) masked) * g + b.  4 rows per block.
// ---------------------------------------------------------------------------
__global__ __launch_bounds__(256) void final_kernel(
    const short* __restrict__ c2, const short* __restrict__ xres,
    const int* __restrict__ mask, const float* __restrict__ g,
    const float* __restrict__ b, float* __restrict__ out)
{
    __shared__ float red[256];
    const int tid = threadIdx.x;
    const int m0 = blockIdx.x * 4;
    const int c0 = tid*2;
    const float2 gg = *(const float2*)(g + c0);
    const float2 bb = *(const float2*)(b + c0);

    for (int rr = 0; rr < 4; ++rr) {
        const int m = m0 + rr;
        const int n = m >> 10, s = m & 1023;
        const int mk = mask[(size_t)n*SS*SS + (size_t)s*SS];

        short2 ca = *(const short2*)(c2 + (size_t)m*CC + c0);
        short2 xa = *(const short2*)(xres + (size_t)m*CC + c0);
        float v0 = fmaxf(s2f(ca.x) + s2f(xa.x), 0.f);
        float v1 = fmaxf(s2f(ca.y) + s2f(xa.y), 0.f);
        if (mk == 0) { v0 = 0.f; v1 = 0.f; }

        red[tid] = v0 + v1;
        __syncthreads();
        for (int off = 128; off > 0; off >>= 1) {
            if (tid < off) red[tid] += red[tid + off];
            __syncthreads();
        }
        float mu = red[0] * (1.0f/512.0f);
        __syncthreads();
        float d0 = v0 - mu, d1 = v1 - mu;
        red[tid] = d0*d0 + d1*d1;
        __syncthreads();
        for (int off = 128; off > 0; off >>= 1) {
            if (tid < off) red[tid] += red[tid + off];
            __syncthreads();
        }
        float rstd = rsqrtf(red[0] * (1.0f/512.0f) + 1e-5f);
        float2 o;
        o.x = d0*rstd*gg.x + bb.x;
        o.y = d1*rstd*gg.y + bb.y;
        *(float2*)(out + (size_t)m*CC + c0) = o;
        __syncthreads();                     // red reuse next row
    }
}

// ---------------------------------------------------------------------------
extern "C" void kernel_launch(void* const* d_in, const int* in_sizes, int n_in,
                              void* d_out, int out_size, void* d_ws, size_t ws_size,
                              hipStream_t stream)
{
    const float* x      = (const float*)d_in[0];
    const int*   mask   = (const int*)  d_in[1];
    const float* Wq     = (const float*)d_in[2];
    const float* Wk     = (const float*)d_in[3];
    const float* Wv     = (const float*)d_in[4];
    const float* pk     = (const float*)d_in[5];
    const float* pv     = (const float*)d_in[6];
    const float* th_pre = (const float*)d_in[7];
    const float* th_post= (const float*)d_in[8];
    const float* fc_w   = (const float*)d_in[9];
    const float* fc_b   = (const float*)d_in[10];
    const float* c1w    = (const float*)d_in[11];
    const float* c1b    = (const float*)d_in[12];
    const float* c2w    = (const float*)d_in[13];
    const float* c2b    = (const float*)d_in[14];
    const float* lng    = (const float*)d_in[15];
    const float* lnb    = (const float*)d_in[16];
    float* out = (float*)d_out;
    (void)in_sizes; (void)n_in; (void)out_size; (void)ws_size;

    char* ws = (char*)d_ws;
    const size_t SZ_Q  = (size_t)BN*HH*SS*DD;      //  4.19 MB (fp8)
    const size_t SZ_K  = (size_t)BN*HH*KT*DD;      //  4.26 MB (fp8)
    const size_t SZ_VT = (size_t)BN*HH*DD*KT;      //  4.26 MB (fp8)
    const size_t SZ_E  = (size_t)BN*SS*HH*KTE;     // 71.3 MB (fp8, raw energy)
    const size_t SZ_A  = (size_t)BN*SS*CC*2;       //  8.39 MB (bf16)
    const size_t SZ_A8 = (size_t)BN*SS*CC;         //  4.19 MB (fp8)

    uchar* qf  = (uchar*)(ws);
    uchar* kf  = (uchar*)(ws + SZ_Q);
    uchar* vt  = (uchar*)(ws + SZ_Q + SZ_K);
    uchar* E   = (uchar*)(ws + SZ_Q + SZ_K + SZ_VT);
    short* AO  = (short*)(ws + SZ_Q + SZ_K + SZ_VT + SZ_E);
    char*  wend = ws + SZ_Q + SZ_K + SZ_VT + SZ_E + SZ_A;
    short* Bfc = (short*)(wend);
    uchar* Bc1 = (uchar*)(wend + 512*512*2);
    uchar* Bc2 = (uchar*)(wend + 512*512*2 + 512*1536);
    short* Bqkv= (short*)(wend + 512*512*2 + 2*512*1536);
    uchar* xres8 = (uchar*)(wend + 512*512*2 + 2*512*1536 + 3*64*64*2);
    short* c2buf = (short*)(wend + 512*512*2 + 2*512*1536 + 3*64*64*2 + SZ_A8);
    // Aliases (dead regions): xres(bf16) over qf+kf (dead after energy);
    // h1(fp8) over E (dead after pv_fused).
    short* xres = (short*)(ws);
    uchar* h18  = (uchar*)E;
    // total ws ~= 106 MB (ws_size >= 256 MiB)

    {
        int total = 512*512 + 2*512*1536 + 3*64*64 + BN*HH*PP*DD;
        prep_kernel<<<(total + 255)/256, 256, 0, stream>>>(
            fc_w, c1w, c2w, Wq, Wk, Wv, th_post, pk, pv,
            Bfc, Bc1, Bc2, Bqkv, kf, vt);
    }
    qkv_mfma<<<BN*SS/64*HH, 256, 0, stream>>>(x, Bqkv, qf, kf, vt);

    energy_mfma8<<<dim3(16, 64), 256, 0, stream>>>(qf, kf, E);
    pv_fused<<<dim3(8, 64), 256, 0, stream>>>(E, vt, mask, th_pre, AO);

    fc_mfma<<<dim3(8, 128), 256, 0, stream>>>(AO, Bfc, fc_b, x, xres, xres8);
    conv_mfma8<<<dim3(8, 128), 256, 0, stream>>>(xres8, Bc1, c1b, h18, (short*)nullptr, 1);
    conv_mfma8<<<dim3(8, 128), 256, 0, stream>>>(h18, Bc2, c2b, (uchar*)nullptr, c2buf, 0);
    final_kernel<<<BN*SS/4, 256, 0, stream>>>(c2buf, xres, mask, lng, lnb, out);
}